// Round 4
// baseline (135.632 us; speedup 1.0000x reference)
//
#include <hip/hip_runtime.h>
#include <hip/hip_bf16.h>
#include <math.h>

constexpr int B = 4;
constexpr int N = 1024;
constexpr float NEGINF = -9000000000000000.0f;

// ---------- wk0: fused weights. Wu = W1@lin_w, Wv = W2@lin_w, bu = W1@lin_b,
// bv = W2@lin_b.  1 block x 512 threads.
__global__ __launch_bounds__(512) void gat_wk0(
    const float* __restrict__ lin_w, const float* __restrict__ lin_b,
    const float* __restrict__ W_w, float* __restrict__ Wu, float* __restrict__ Wv,
    float* __restrict__ bu, float* __restrict__ bv) {
  __shared__ float lw[64 * 68];   // [o][i]
  __shared__ float ww[64 * 132];  // [f][o2]
  __shared__ float lb[64];
  const int tid = threadIdx.x;
  for (int idx = tid; idx < 4096; idx += 512)
    lw[(idx >> 6) * 68 + (idx & 63)] = lin_w[idx];
  for (int idx = tid; idx < 8192; idx += 512)
    ww[(idx >> 7) * 132 + (idx & 127)] = W_w[idx];
  if (tid < 64) lb[tid] = lin_b[tid];
  __syncthreads();

  const int f = tid >> 3, i0 = (tid & 7) << 3;
  float wua[8], wva[8];
#pragma unroll
  for (int r = 0; r < 8; ++r) { wua[r] = 0.f; wva[r] = 0.f; }
  float bup = 0.f, bvp = 0.f;
#pragma unroll 4
  for (int o = 0; o < 64; ++o) {
    const float w1 = ww[f * 132 + o];
    const float w2 = ww[f * 132 + 64 + o];
    const float4 A = *(const float4*)&lw[o * 68 + i0];
    const float4 Bv = *(const float4*)&lw[o * 68 + i0 + 4];
    const float lv[8] = {A.x, A.y, A.z, A.w, Bv.x, Bv.y, Bv.z, Bv.w};
#pragma unroll
    for (int r = 0; r < 8; ++r) {
      wua[r] = fmaf(w1, lv[r], wua[r]);
      wva[r] = fmaf(w2, lv[r], wva[r]);
    }
    bup = fmaf(w1, lb[o], bup);
    bvp = fmaf(w2, lb[o], bvp);
  }
  *(float4*)&Wu[f * 64 + i0] = make_float4(wua[0], wua[1], wua[2], wua[3]);
  *(float4*)&Wu[f * 64 + i0 + 4] = make_float4(wua[4], wua[5], wua[6], wua[7]);
  *(float4*)&Wv[f * 64 + i0] = make_float4(wva[0], wva[1], wva[2], wva[3]);
  *(float4*)&Wv[f * 64 + i0 + 4] = make_float4(wva[4], wva[5], wva[6], wva[7]);
  if ((tid & 7) == 0) { bu[f] = bup; bv[f] = bvp; }
}

// ---------- prep: hp = h@lin_w^T+lin_b ; u = h@Wu^T+bu ; v = h@Wv^T+bv ;
// au = a.u ; av = a.v ; vT transposed.  128 blocks (b x 32-row tile) x 256 thr.
__global__ __launch_bounds__(256) void gat_prep(
    const float* __restrict__ h, const float* __restrict__ lin_w,
    const float* __restrict__ lin_b, const float* __restrict__ a_g,
    const float* __restrict__ Wu, const float* __restrict__ Wv,
    const float* __restrict__ bu_g, const float* __restrict__ bv_g,
    float* __restrict__ hp, float* __restrict__ u_out, float* __restrict__ vT,
    float* __restrict__ au_out, float* __restrict__ av_out) {
  __shared__ float hs[64 * 34];   // [k][n]
  __shared__ float wl[64 * 68];   // [k][f]
  __shared__ float wu[64 * 68];
  __shared__ float wv[64 * 68];
  __shared__ float vt_s[64 * 33]; // [f][n]
  __shared__ float ared[2][32 * 17];
  __shared__ float lb_s[64], bu_s[64], bv_s[64], a_s[64];

  const int b = blockIdx.x >> 5;
  const int n0 = (blockIdx.x & 31) << 5;
  const int tid = threadIdx.x;

  for (int idx = tid; idx < 2048; idx += 256) {
    const int r = idx >> 6, c = idx & 63;
    hs[c * 34 + r] = h[((b << 10) + n0 + r) * 64 + c];
  }
  for (int idx = tid; idx < 4096; idx += 256) {
    const int r = idx >> 6, c = idx & 63;
    wl[c * 68 + r] = lin_w[idx];
    wu[c * 68 + r] = Wu[idx];
    wv[c * 68 + r] = Wv[idx];
  }
  if (tid < 64) {
    lb_s[tid] = lin_b[tid]; bu_s[tid] = bu_g[tid];
    bv_s[tid] = bv_g[tid];  a_s[tid] = a_g[tid];
  }
  __syncthreads();

  const int tf = tid & 15, tn = tid >> 4;  // rows 2tn..2tn+1, cols 4tf..4tf+3
  float ahp[2][4], aU[2][4], aV[2][4];
#pragma unroll
  for (int q = 0; q < 2; ++q)
#pragma unroll
    for (int r = 0; r < 4; ++r) {
      ahp[q][r] = lb_s[tf * 4 + r];
      aU[q][r] = bu_s[tf * 4 + r];
      aV[q][r] = bv_s[tf * 4 + r];
    }
#pragma unroll 4
  for (int k = 0; k < 64; ++k) {
    const float2 h2 = *(const float2*)&hs[k * 34 + tn * 2];
    const float hv[2] = {h2.x, h2.y};
    const float4 l4 = *(const float4*)&wl[k * 68 + tf * 4];
    const float4 u4 = *(const float4*)&wu[k * 68 + tf * 4];
    const float4 v4 = *(const float4*)&wv[k * 68 + tf * 4];
    const float lv[4] = {l4.x, l4.y, l4.z, l4.w};
    const float uv[4] = {u4.x, u4.y, u4.z, u4.w};
    const float vv[4] = {v4.x, v4.y, v4.z, v4.w};
#pragma unroll
    for (int q = 0; q < 2; ++q)
#pragma unroll
      for (int r = 0; r < 4; ++r) {
        ahp[q][r] = fmaf(hv[q], lv[r], ahp[q][r]);
        aU[q][r] = fmaf(hv[q], uv[r], aU[q][r]);
        aV[q][r] = fmaf(hv[q], vv[r], aV[q][r]);
      }
  }
#pragma unroll
  for (int q = 0; q < 2; ++q) {
    const int row = (b << 10) + n0 + tn * 2 + q;
    *(float4*)&hp[row * 64 + tf * 4] =
        make_float4(ahp[q][0], ahp[q][1], ahp[q][2], ahp[q][3]);
    *(float4*)&u_out[row * 64 + tf * 4] =
        make_float4(aU[q][0], aU[q][1], aU[q][2], aU[q][3]);
  }
  float aup[2] = {0.f, 0.f}, avp[2] = {0.f, 0.f};
#pragma unroll
  for (int q = 0; q < 2; ++q)
#pragma unroll
    for (int r = 0; r < 4; ++r) {
      vt_s[(tf * 4 + r) * 33 + tn * 2 + q] = aV[q][r];
      aup[q] = fmaf(a_s[tf * 4 + r], aU[q][r], aup[q]);
      avp[q] = fmaf(a_s[tf * 4 + r], aV[q][r], avp[q]);
    }
#pragma unroll
  for (int q = 0; q < 2; ++q) {
    ared[0][(tn * 2 + q) * 17 + tf] = aup[q];
    ared[1][(tn * 2 + q) * 17 + tf] = avp[q];
  }
  __syncthreads();
  for (int idx = tid; idx < 2048; idx += 256) {
    const int f = idx >> 5, n = idx & 31;
    vT[(((b << 6) + f) << 10) + n0 + n] = vt_s[f * 33 + n];
  }
  if (tid < 64) {
    const int which = tid >> 5, row = tid & 31;
    float s2 = 0.f;
#pragma unroll
    for (int t = 0; t < 16; ++t) s2 += ared[which][row * 17 + t];
    if (which == 0) au_out[(b << 10) + n0 + row] = s2;
    else av_out[(b << 10) + n0 + row] = s2;
  }
}

// ---------- attn: e = 0.6(au+av)+0.4*sum_f a|u+v| -> mask -> softmax -> PV -> ELU
// 512 blocks (b x 8-row tile) x 256 threads; j ownership strided (tid+256k).
__global__ __launch_bounds__(256) void gat_attn(
    const float* __restrict__ u_g, const float* __restrict__ vT,
    const float* __restrict__ hp, const int* __restrict__ adj,
    const float* __restrict__ a_g, const float* __restrict__ au_g,
    const float* __restrict__ av_g, float* __restrict__ out) {
  __shared__ float p_s[2 * 1024 * 4];  // [iq][j][4] : 32 KB (reused as red)
  __shared__ float u_s[64 * 8];        // [f][i]
  __shared__ float a_s[64];
  __shared__ float au_s[8];
  __shared__ float wred[4 * 8];
  __shared__ float wsum[4 * 8];
  __shared__ float rinv_s[8];

  const int b = blockIdx.x >> 7;
  const int i0 = (blockIdx.x & 127) << 3;
  const int tid = threadIdx.x;
  const int lane = tid & 63, w = tid >> 6;

  if (tid < 64) a_s[tid] = a_g[tid];
  if (tid < 8) au_s[tid] = au_g[(b << 10) + i0 + tid];
  for (int idx = tid; idx < 512; idx += 256) {
    const int i = idx >> 6, f = idx & 63;
    u_s[f * 8 + i] = u_g[((b << 10) + i0 + i) * 64 + f];
  }
  __syncthreads();

  // ---- Phase 1: d[i][k] = sum_f a_f * |u_if + v_jf|, j = tid + 256k ----
  float e[8][4];
#pragma unroll
  for (int i = 0; i < 8; ++i)
#pragma unroll
    for (int k = 0; k < 4; ++k) e[i][k] = 0.f;

  const float* vb = vT + ((b << 6) << 10);
#pragma unroll 2
  for (int f = 0; f < 64; ++f) {
    const float af = a_s[f];
    float vv[4];
#pragma unroll
    for (int k = 0; k < 4; ++k) vv[k] = vb[(f << 10) + tid + (k << 8)];
    const float4 ua = *(const float4*)&u_s[f * 8];
    const float4 ub = *(const float4*)&u_s[f * 8 + 4];
    const float uu[8] = {ua.x, ua.y, ua.z, ua.w, ub.x, ub.y, ub.z, ub.w};
#pragma unroll
    for (int i = 0; i < 8; ++i)
#pragma unroll
      for (int k = 0; k < 4; ++k)
        e[i][k] = fmaf(af, fabsf(uu[i] + vv[k]), e[i][k]);
  }
  // e = 0.6(au+av) + 0.4 d, then adjacency mask
  float avv[4];
#pragma unroll
  for (int k = 0; k < 4; ++k)
    avv[k] = 0.6f * av_g[(b << 10) + tid + (k << 8)];
  float au6[8];
#pragma unroll
  for (int i = 0; i < 8; ++i) au6[i] = 0.6f * au_s[i];
  const int* adjb = adj + ((((b << 10) + i0)) << 10) + tid;
#pragma unroll
  for (int i = 0; i < 8; ++i)
#pragma unroll
    for (int k = 0; k < 4; ++k) {
      const float ev = fmaf(0.4f, e[i][k], au6[i] + avv[k]);
      e[i][k] = adjb[(i << 10) + (k << 8)] > 0 ? ev : NEGINF;
    }

  // ---- Phase 2: softmax in registers ----
#pragma unroll
  for (int i = 0; i < 8; ++i) {
    float mm = fmaxf(fmaxf(e[i][0], e[i][1]), fmaxf(e[i][2], e[i][3]));
#pragma unroll
    for (int off = 32; off; off >>= 1) mm = fmaxf(mm, __shfl_xor(mm, off));
    if (lane == 0) wred[w * 8 + i] = mm;
  }
  __syncthreads();
#pragma unroll
  for (int i = 0; i < 8; ++i) {
    const float mi = fmaxf(fmaxf(wred[i], wred[8 + i]),
                           fmaxf(wred[16 + i], wred[24 + i]));
#pragma unroll
    for (int k = 0; k < 4; ++k) e[i][k] = __expf(e[i][k] - mi);
    float ss = e[i][0] + e[i][1] + e[i][2] + e[i][3];
#pragma unroll
    for (int off = 32; off; off >>= 1) ss += __shfl_xor(ss, off);
    if (lane == 0) wsum[w * 8 + i] = ss;
  }
  __syncthreads();
#pragma unroll
  for (int i = 0; i < 8; ++i) {
    const float stot = wsum[i] + wsum[8 + i] + wsum[16 + i] + wsum[24 + i];
    if (tid == i) rinv_s[i] = 1.0f / stot;
  }
  // write p to LDS: [iq][j][4], conflict-free float4 stores
#pragma unroll
  for (int k = 0; k < 4; ++k) {
    const int j = tid + (k << 8);
    *(float4*)&p_s[j << 2] = make_float4(e[0][k], e[1][k], e[2][k], e[3][k]);
    *(float4*)&p_s[4096 + (j << 2)] =
        make_float4(e[4][k], e[5][k], e[6][k], e[7][k]);
  }
  __syncthreads();

  // ---- Phase 3: h' = p @ hp ----
  const int fl = tid & 63, g = tid >> 6;
  float acc[8];
#pragma unroll
  for (int i = 0; i < 8; ++i) acc[i] = 0.f;
  const float* hpb = hp + (b << 16);
#pragma unroll 4
  for (int jj = g << 8; jj < (g << 8) + 256; ++jj) {
    const float hv = hpb[(jj << 6) + fl];
    const float4 p0 = *(const float4*)&p_s[jj << 2];
    const float4 p1 = *(const float4*)&p_s[4096 + (jj << 2)];
    acc[0] = fmaf(p0.x, hv, acc[0]);
    acc[1] = fmaf(p0.y, hv, acc[1]);
    acc[2] = fmaf(p0.z, hv, acc[2]);
    acc[3] = fmaf(p0.w, hv, acc[3]);
    acc[4] = fmaf(p1.x, hv, acc[4]);
    acc[5] = fmaf(p1.y, hv, acc[5]);
    acc[6] = fmaf(p1.z, hv, acc[6]);
    acc[7] = fmaf(p1.w, hv, acc[7]);
  }
  __syncthreads();               // p_s reads done; reuse as reduction buffer
  float* red = p_s;
#pragma unroll
  for (int i = 0; i < 8; ++i) red[((g << 3) + i) << 6 | fl] = acc[i];
  __syncthreads();
#pragma unroll
  for (int o = 0; o < 2; ++o) {
    const int idx = tid + (o << 8);
    const int i = idx >> 6, f = idx & 63;
    float r = red[(i << 6) + f] + red[((8 + i) << 6) + f] +
              red[((16 + i) << 6) + f] + red[((24 + i) << 6) + f];
    r *= rinv_s[i];
    out[((b << 10) + i0 + i) * 64 + f] = r > 0.f ? r : expm1f(r);
  }
}

extern "C" void kernel_launch(void* const* d_in, const int* in_sizes, int n_in,
                              void* d_out, int out_size, void* d_ws, size_t ws_size,
                              hipStream_t stream) {
  const float* h = (const float*)d_in[0];
  const int* adj = (const int*)d_in[1];
  const float* lin_w = (const float*)d_in[2];
  const float* lin_b = (const float*)d_in[3];
  const float* W_w = (const float*)d_in[4];
  const float* a = (const float*)d_in[5];
  float* outp = (float*)d_out;

  float* ws = (float*)d_ws;
  float* hp = ws;                 // 262144
  float* u = ws + 262144;         // 262144
  float* vT = ws + 524288;        // 262144
  float* au = ws + 786432;        // 4096
  float* av = ws + 790528;        // 4096
  float* Wu = ws + 794624;        // 4096
  float* Wv = ws + 798720;        // 4096
  float* bu = ws + 802816;        // 64
  float* bv = ws + 802880;        // 64

  gat_wk0<<<dim3(1), dim3(512), 0, stream>>>(lin_w, lin_b, W_w, Wu, Wv, bu, bv);
  gat_prep<<<dim3(128), dim3(256), 0, stream>>>(h, lin_w, lin_b, a, Wu, Wv, bu,
                                                bv, hp, u, vT, au, av);
  gat_attn<<<dim3(512), dim3(256), 0, stream>>>(u, vT, hp, adj, a, au, av, outp);
}

// Round 6
// 119.289 us; speedup vs baseline: 1.1370x; 1.1370x over previous
//
#include <hip/hip_runtime.h>
#include <hip/hip_bf16.h>
#include <math.h>

constexpr int B = 4;
constexpr int N = 1024;
constexpr float NEGINF = -9000000000000000.0f;

// ---------- prep: per 32-row tile (128 blocks x 256 thr):
//   pass1: hp = h@lin_w^T + lin_b          (tile kept in LDS, stored global)
//   pass2: u = hp@W1^T, v = hp@W2^T, au = u.a, av = v.a, vT = v transposed
__global__ __launch_bounds__(256) void gat_prep(
    const float* __restrict__ h, const float* __restrict__ lin_w,
    const float* __restrict__ lin_b, const float* __restrict__ W_w,
    const float* __restrict__ a_g,
    float* __restrict__ hp, float* __restrict__ u_out, float* __restrict__ vT,
    float* __restrict__ au_out, float* __restrict__ av_out) {
  __shared__ float hs[64 * 34];    // [k][n] h^T tile
  __shared__ float wl[64 * 68];    // [k][f] lin_w^T
  __shared__ float w1[64 * 68];    // [f][o] W1^T : w1[f*68+o] = W_w[o*128+f]
  __shared__ float w2[64 * 68];    // [f][o] W2^T
  __shared__ float hpT[64 * 34];   // [f][n]
  __shared__ float vt_s[64 * 33];  // [o][n]
  __shared__ float ared[2][32 * 17];
  __shared__ float lb_s[64], a_s[64];

  const int b = blockIdx.x >> 5;
  const int n0 = (blockIdx.x & 31) << 5;
  const int tid = threadIdx.x;

  for (int idx = tid; idx < 2048; idx += 256) {
    const int r = idx >> 6, c = idx & 63;
    hs[c * 34 + r] = h[((b << 10) + n0 + r) * 64 + c];
  }
  for (int idx = tid; idx < 4096; idx += 256) {
    const int o = idx >> 6, f = idx & 63;
    wl[f * 68 + o] = lin_w[idx];              // lin_w[o][f] -> [f][o]... (k=f)
    w1[f * 68 + o] = W_w[o * 128 + f];
    w2[f * 68 + o] = W_w[o * 128 + 64 + f];
  }
  if (tid < 64) { lb_s[tid] = lin_b[tid]; a_s[tid] = a_g[tid]; }
  __syncthreads();

  const int tf = tid & 15, tn = tid >> 4;  // rows 2tn..2tn+1, cols 4tf..4tf+3
  // ---- pass 1: hp ----
  float ahp[2][4];
#pragma unroll
  for (int q = 0; q < 2; ++q)
#pragma unroll
    for (int r = 0; r < 4; ++r) ahp[q][r] = lb_s[tf * 4 + r];
#pragma unroll 4
  for (int k = 0; k < 64; ++k) {
    const float2 h2 = *(const float2*)&hs[k * 34 + tn * 2];
    const float4 l4 = *(const float4*)&wl[k * 68 + tf * 4];
    const float hv[2] = {h2.x, h2.y};
    const float lv[4] = {l4.x, l4.y, l4.z, l4.w};
#pragma unroll
    for (int q = 0; q < 2; ++q)
#pragma unroll
      for (int r = 0; r < 4; ++r) ahp[q][r] = fmaf(hv[q], lv[r], ahp[q][r]);
  }
#pragma unroll
  for (int q = 0; q < 2; ++q) {
    const int row = (b << 10) + n0 + tn * 2 + q;
    *(float4*)&hp[row * 64 + tf * 4] =
        make_float4(ahp[q][0], ahp[q][1], ahp[q][2], ahp[q][3]);
#pragma unroll
    for (int r = 0; r < 4; ++r) hpT[(tf * 4 + r) * 34 + tn * 2 + q] = ahp[q][r];
  }
  __syncthreads();

  // ---- pass 2: u, v from hpT ----
  float aU[2][4] = {}, aV[2][4] = {};
#pragma unroll 4
  for (int k = 0; k < 64; ++k) {
    const float2 h2 = *(const float2*)&hpT[k * 34 + tn * 2];
    const float4 u4 = *(const float4*)&w1[k * 68 + tf * 4];
    const float4 v4 = *(const float4*)&w2[k * 68 + tf * 4];
    const float hv[2] = {h2.x, h2.y};
    const float uv[4] = {u4.x, u4.y, u4.z, u4.w};
    const float vv[4] = {v4.x, v4.y, v4.z, v4.w};
#pragma unroll
    for (int q = 0; q < 2; ++q)
#pragma unroll
      for (int r = 0; r < 4; ++r) {
        aU[q][r] = fmaf(hv[q], uv[r], aU[q][r]);
        aV[q][r] = fmaf(hv[q], vv[r], aV[q][r]);
      }
  }
#pragma unroll
  for (int q = 0; q < 2; ++q) {
    const int row = (b << 10) + n0 + tn * 2 + q;
    *(float4*)&u_out[row * 64 + tf * 4] =
        make_float4(aU[q][0], aU[q][1], aU[q][2], aU[q][3]);
  }
  float aup[2] = {0.f, 0.f}, avp[2] = {0.f, 0.f};
#pragma unroll
  for (int q = 0; q < 2; ++q)
#pragma unroll
    for (int r = 0; r < 4; ++r) {
      vt_s[(tf * 4 + r) * 33 + tn * 2 + q] = aV[q][r];
      aup[q] = fmaf(a_s[tf * 4 + r], aU[q][r], aup[q]);
      avp[q] = fmaf(a_s[tf * 4 + r], aV[q][r], avp[q]);
    }
#pragma unroll
  for (int q = 0; q < 2; ++q) {
    ared[0][(tn * 2 + q) * 17 + tf] = aup[q];
    ared[1][(tn * 2 + q) * 17 + tf] = avp[q];
  }
  __syncthreads();
  for (int idx = tid; idx < 2048; idx += 256) {
    const int f = idx >> 5, n = idx & 31;
    vT[(((b << 6) + f) << 10) + n0 + n] = vt_s[f * 33 + n];
  }
  if (tid < 64) {
    const int which = tid >> 5, row = tid & 31;
    float s2 = 0.f;
#pragma unroll
    for (int t = 0; t < 16; ++t) s2 += ared[which][row * 17 + t];
    if (which == 0) au_out[(b << 10) + n0 + row] = s2;
    else av_out[(b << 10) + n0 + row] = s2;
  }
}

// ---------- attn: e = 0.6(au+av)+0.4*sum_f a|u+v| -> mask -> softmax -> PV -> ELU
// 1024 blocks (b x 4-row tile) x 256 threads; thread owns j = 4*tid .. 4*tid+3.
__global__ __launch_bounds__(256) void gat_attn(
    const float* __restrict__ u_g, const float* __restrict__ vT,
    const float* __restrict__ hp, const int* __restrict__ adj,
    const float* __restrict__ a_g, const float* __restrict__ au_g,
    const float* __restrict__ av_g, float* __restrict__ out) {
  __shared__ float p_s[4 * 1024];  // [i][j] 16 KB (reused as reduction buffer)
  __shared__ float u_s[64 * 4];    // [f][i]
  __shared__ float a_s[64];
  __shared__ float au_s[4];
  __shared__ float wred[4][4];     // [wave][i]
  __shared__ float wsum[4][4];
  __shared__ float rinv_s[4];

  const int b = blockIdx.x >> 8;
  const int i0 = (blockIdx.x & 255) << 2;
  const int tid = threadIdx.x;
  const int lane = tid & 63, w = tid >> 6;
  const int j0 = tid << 2;

  if (tid < 64) a_s[tid] = a_g[tid];
  if (tid < 4) au_s[tid] = au_g[(b << 10) + i0 + tid];
  {
    const int i = tid >> 6, f = tid & 63;
    u_s[f * 4 + i] = u_g[((b << 10) + i0 + i) * 64 + f];
  }
  __syncthreads();

  // ---- Phase 1: d[i][k] = sum_f a_f * |u_if + v_(j0+k)f| ----
  float e[4][4];
#pragma unroll
  for (int i = 0; i < 4; ++i)
#pragma unroll
    for (int k = 0; k < 4; ++k) e[i][k] = 0.f;

  const float* vb = vT + ((b << 6) << 10);
#pragma unroll 4
  for (int f = 0; f < 64; ++f) {
    const float af = a_s[f];
    const float4 v4 = *(const float4*)&vb[(f << 10) + j0];
    const float4 u4 = *(const float4*)&u_s[f * 4];
    const float uu[4] = {u4.x, u4.y, u4.z, u4.w};
    const float vv[4] = {v4.x, v4.y, v4.z, v4.w};
#pragma unroll
    for (int i = 0; i < 4; ++i)
#pragma unroll
      for (int k = 0; k < 4; ++k)
        e[i][k] = fmaf(af, fabsf(uu[i] + vv[k]), e[i][k]);
  }
  // e = 0.6(au+av) + 0.4 d, then adjacency mask (int4 per row)
  const float4 av4 = *(const float4*)&av_g[(b << 10) + j0];
  const float avv[4] = {0.6f * av4.x, 0.6f * av4.y, 0.6f * av4.z, 0.6f * av4.w};
  float au6[4];
#pragma unroll
  for (int i = 0; i < 4; ++i) au6[i] = 0.6f * au_s[i];
  const int* adjb = adj + ((((b << 10) + i0)) << 10) + j0;
#pragma unroll
  for (int i = 0; i < 4; ++i) {
    const int4 ad = *(const int4*)&adjb[i << 10];
    const int adv[4] = {ad.x, ad.y, ad.z, ad.w};
#pragma unroll
    for (int k = 0; k < 4; ++k) {
      const float ev = fmaf(0.4f, e[i][k], au6[i] + avv[k]);
      e[i][k] = adv[k] > 0 ? ev : NEGINF;
    }
  }

  // ---- Phase 2: softmax in registers ----
#pragma unroll
  for (int i = 0; i < 4; ++i) {
    float mm = fmaxf(fmaxf(e[i][0], e[i][1]), fmaxf(e[i][2], e[i][3]));
#pragma unroll
    for (int off = 32; off; off >>= 1) mm = fmaxf(mm, __shfl_xor(mm, off));
    if (lane == 0) wred[w][i] = mm;
  }
  __syncthreads();
#pragma unroll
  for (int i = 0; i < 4; ++i) {
    const float mi = fmaxf(fmaxf(wred[0][i], wred[1][i]),
                           fmaxf(wred[2][i], wred[3][i]));
#pragma unroll
    for (int k = 0; k < 4; ++k) e[i][k] = __expf(e[i][k] - mi);
    float ss = e[i][0] + e[i][1] + e[i][2] + e[i][3];
#pragma unroll
    for (int off = 32; off; off >>= 1) ss += __shfl_xor(ss, off);
    if (lane == 0) wsum[w][i] = ss;
  }
  __syncthreads();
  if (tid < 4)
    rinv_s[tid] = 1.0f / (wsum[0][tid] + wsum[1][tid] + wsum[2][tid] + wsum[3][tid]);
  // p to LDS: [i][j] planes, float4 stores at lane-stride 16B (conflict-free)
#pragma unroll
  for (int i = 0; i < 4; ++i)
    *(float4*)&p_s[(i << 10) + j0] = make_float4(e[i][0], e[i][1], e[i][2], e[i][3]);
  __syncthreads();

  // ---- Phase 3: h' = p @ hp ; thread = (f, j-group of 256) ----
  const int fl = tid & 63, g = tid >> 6;
  float acc[4] = {0.f, 0.f, 0.f, 0.f};
  const float* hpb = hp + (b << 16);
  for (int jj = g << 8; jj < (g << 8) + 256; jj += 4) {
    const float4 p0 = *(const float4*)&p_s[jj];
    const float4 p1 = *(const float4*)&p_s[1024 + jj];
    const float4 p2 = *(const float4*)&p_s[2048 + jj];
    const float4 p3 = *(const float4*)&p_s[3072 + jj];
    float hv[4];
#pragma unroll
    for (int t = 0; t < 4; ++t) hv[t] = hpb[((jj + t) << 6) + fl];
    acc[0] += p0.x * hv[0] + p0.y * hv[1] + p0.z * hv[2] + p0.w * hv[3];
    acc[1] += p1.x * hv[0] + p1.y * hv[1] + p1.z * hv[2] + p1.w * hv[3];
    acc[2] += p2.x * hv[0] + p2.y * hv[1] + p2.z * hv[2] + p2.w * hv[3];
    acc[3] += p3.x * hv[0] + p3.y * hv[1] + p3.z * hv[2] + p3.w * hv[3];
  }
  __syncthreads();  // p_s reads done; reuse as reduction buffer [g*4+i][f]
  float* red = p_s;
#pragma unroll
  for (int i = 0; i < 4; ++i) red[(((g << 2) + i) << 6) + fl] = acc[i];
  __syncthreads();
  {
    const int i = tid >> 6, f = tid & 63;
    float r = red[((i) << 6) + f] + red[((4 + i) << 6) + f] +
              red[((8 + i) << 6) + f] + red[((12 + i) << 6) + f];
    r *= rinv_s[i];
    out[((b << 10) + i0 + i) * 64 + f] = r > 0.f ? r : expm1f(r);
  }
}

extern "C" void kernel_launch(void* const* d_in, const int* in_sizes, int n_in,
                              void* d_out, int out_size, void* d_ws, size_t ws_size,
                              hipStream_t stream) {
  const float* h = (const float*)d_in[0];
  const int* adj = (const int*)d_in[1];
  const float* lin_w = (const float*)d_in[2];
  const float* lin_b = (const float*)d_in[3];
  const float* W_w = (const float*)d_in[4];
  const float* a = (const float*)d_in[5];
  float* outp = (float*)d_out;

  float* ws = (float*)d_ws;
  float* hp = ws;                 // 262144
  float* u = ws + 262144;         // 262144
  float* vT = ws + 524288;        // 262144
  float* au = ws + 786432;        // 4096
  float* av = ws + 790528;        // 4096

  gat_prep<<<dim3(128), dim3(256), 0, stream>>>(h, lin_w, lin_b, W_w, a,
                                                hp, u, vT, au, av);
  gat_attn<<<dim3(1024), dim3(256), 0, stream>>>(u, vT, hp, adj, a, au, av, outp);
}